// Round 2
// baseline (223.653 us; speedup 1.0000x reference)
//
#include <hip/hip_runtime.h>
#include <hip/hip_cooperative_groups.h>

namespace cg = cooperative_groups;

// Rejection sampler, cooperative full-chip version.
// B=64 batches x C=8 chunk-blocks = 512 blocks (2/CU), 512 threads each.
// Phase 1: redundant parallel reject-chain + chunk load into REGISTERS + partial sum.
// grid.sync()
// Phase 2: cross-block exclusive prefix from partials, count cdf<T from registers.
// grid.sync()
// Phase 3: c==0 blocks write the 9 output ints per batch.

constexpr int BB  = 64;
constexpr int SS  = 8;
constexpr int VV  = 32000;
constexpr int C   = 8;            // blocks per batch
constexpr int NTH = 512;
constexpr int NW  = NTH / 64;
constexpr int CHUNK = VV / C;     // 4000 floats per block
constexpr int PT  = 8;            // floats per thread (2 x float4)
constexpr int ACT = CHUNK / PT;   // 500 active threads

__global__ __launch_bounds__(NTH, 4) void rs_coop(
    const float* __restrict__ target,  // B x (S+1) x V
    const float* __restrict__ draft,   // B x S x V
    const int*   __restrict__ ids,     // B x S
    const float* __restrict__ ru,      // B x S
    const float* __restrict__ su,      // B
    int*         __restrict__ out,     // B x (S+1)
    float*       __restrict__ partial, // B x C   (workspace)
    int*         __restrict__ count)   // B       (workspace)
{
    const int blk  = blockIdx.x;
    const int b    = blk >> 3;        // /C
    const int c    = blk & (C - 1);
    const int tid  = threadIdx.x;
    const int lane = tid & 63;
    const int wid  = tid >> 6;

    __shared__ int   s_rj;
    __shared__ float s_wtot[NW];

    // --- reject chain: lanes 0..7 of wave 0 gather in parallel, ballot+ffs ---
    if (wid == 0) {
        bool rejflag = false;
        if (lane < SS) {
            int   tok = ids[b * SS + lane];
            float t   = target[((size_t)b * (SS + 1) + lane) * VV + tok];
            float d   = draft [((size_t)b * SS       + lane) * VV + tok];
            float r   = ru[b * SS + lane];
            rejflag = (t / d) < r;
        }
        unsigned long long m = __ballot(rejflag);
        if (lane == 0) s_rj = m ? (int)(__ffsll((long long)m) - 1) : SS;
    }
    __syncthreads();

    const int  rj    = s_rj;
    const bool bonus = (rj == SS);
    const float* __restrict__ trow =
        target + ((size_t)b * (SS + 1) + rj) * VV + (size_t)c * CHUNK;
    const float* __restrict__ drow =
        draft  + ((size_t)b * SS + (bonus ? 0 : rj)) * VV + (size_t)c * CHUNK;

    // --- phase 1: load chunk into registers, per-thread sum ---
    float q[PT];
    #pragma unroll
    for (int k = 0; k < PT; ++k) q[k] = 0.f;
    float lsum = 0.f;

    if (tid < ACT) {
        const float4* t4 = reinterpret_cast<const float4*>(trow) + tid * 2;
        const float4* d4 = reinterpret_cast<const float4*>(drow) + tid * 2;
        #pragma unroll
        for (int k = 0; k < 2; ++k) {
            float4 t = t4[k];
            if (bonus) {
                q[4*k+0] = t.x; q[4*k+1] = t.y; q[4*k+2] = t.z; q[4*k+3] = t.w;
            } else {
                float4 d = d4[k];
                q[4*k+0] = fmaxf(t.x - d.x, 0.f);
                q[4*k+1] = fmaxf(t.y - d.y, 0.f);
                q[4*k+2] = fmaxf(t.z - d.z, 0.f);
                q[4*k+3] = fmaxf(t.w - d.w, 0.f);
            }
            lsum += q[4*k+0] + q[4*k+1] + q[4*k+2] + q[4*k+3];
        }
    }

    // wave-level inclusive scan of per-thread sums
    float v = lsum;
    #pragma unroll
    for (int d = 1; d < 64; d <<= 1) {
        float n = __shfl_up(v, d, 64);
        if (lane >= d) v += n;
    }
    if (lane == 63) s_wtot[wid] = v;
    __syncthreads();

    float woff = 0.f, bsum = 0.f;
    #pragma unroll
    for (int w = 0; w < NW; ++w) {
        float wt = s_wtot[w];
        if (w < wid) woff += wt;
        bsum += wt;
    }

    if (tid == 0) partial[blk] = bsum;          // partial[b*C + c]
    if (c == 0 && tid == 0) atomicExch(&count[b], 0);
    __threadfence();

    cg::this_grid().sync();

    // --- phase 2: cross-block exclusive prefix, count from registers ---
    float excl_blk = 0.f, total = 0.f;
    #pragma unroll
    for (int j = 0; j < C; ++j) {
        float p = partial[b * C + j];
        if (j < c) excl_blk += p;
        total += p;
    }
    const float T = su[b] * total;
    float running = excl_blk + woff + (v - lsum);   // global exclusive prefix

    int cnt = 0;
    if (tid < ACT) {
        #pragma unroll
        for (int k = 0; k < PT; ++k) {
            running += q[k];
            cnt += (running < T) ? 1 : 0;
        }
    }
    #pragma unroll
    for (int off = 32; off > 0; off >>= 1) cnt += __shfl_down(cnt, off, 64);
    if (lane == 0 && cnt) atomicAdd(&count[b], cnt);
    __threadfence();

    cg::this_grid().sync();

    // --- phase 3: write outputs (block c==0 of each batch) ---
    if (c == 0 && tid <= SS) {
        int sampled = min(atomicAdd(&count[b], 0), VV - 1);
        int val = (tid < rj) ? ids[b * SS + tid]
                             : ((tid == rj) ? sampled : -1);
        out[b * (SS + 1) + tid] = val;
    }
}

extern "C" void kernel_launch(void* const* d_in, const int* in_sizes, int n_in,
                              void* d_out, int out_size, void* d_ws, size_t ws_size,
                              hipStream_t stream) {
    const float* target = (const float*)d_in[0];
    const float* draft  = (const float*)d_in[1];
    const int*   ids    = (const int*)  d_in[2];
    const float* ru     = (const float*)d_in[3];
    const float* su     = (const float*)d_in[4];
    int* out = (int*)d_out;

    float* partial = (float*)d_ws;                       // BB*C floats
    int*   count   = (int*)((char*)d_ws + BB * C * sizeof(float));

    void* args[] = { (void*)&target, (void*)&draft, (void*)&ids, (void*)&ru,
                     (void*)&su, (void*)&out, (void*)&partial, (void*)&count };
    hipLaunchCooperativeKernel((const void*)rs_coop, dim3(BB * C), dim3(NTH),
                               args, 0, stream);
}

// Round 3
// 16.293 us; speedup vs baseline: 13.7271x; 13.7271x over previous
//
#include <hip/hip_runtime.h>

// Rejection sampler, two-kernel full-chip version (stream-ordered, no grid.sync).
// B=64, S=8, V=32000. Grid = B*C = 512 blocks (C=8 chunks per batch), 512 thr.
//
// k1: redundant parallel reject-chain per block; partial chunk sum -> ws.
// k2: re-read chunk (cache-hot), global exclusive prefix via ws partials,
//     count cdf < u*total; last-arriving block per batch writes the 9 outputs
//     (packed atomic: bits[0:19]=count sum, bits[20:]=arrival counter).
//
// Normalization denominators cancel in the CDF-inversion count, so all work is
// in un-normalized p-space: count = #{ i : cumsum(p)_i < u * sum(p) }.

constexpr int BB  = 64;
constexpr int SS  = 8;
constexpr int VV  = 32000;
constexpr int C   = 8;             // blocks per batch
constexpr int NTH = 512;
constexpr int NW  = NTH / 64;
constexpr int CHUNK = VV / C;      // 4000 floats
constexpr int PT  = 8;             // floats per thread
constexpr int ACT = CHUNK / PT;    // 500 active threads

__global__ __launch_bounds__(NTH) void rs_k1(
    const float* __restrict__ target, const float* __restrict__ draft,
    const int* __restrict__ ids, const float* __restrict__ ru,
    int* __restrict__ rj_ws, float* __restrict__ partial,
    unsigned int* __restrict__ count)
{
    const int blk = blockIdx.x, b = blk >> 3, c = blk & (C - 1);
    const int tid = threadIdx.x, lane = tid & 63, wid = tid >> 6;
    __shared__ int   s_rj;
    __shared__ float s_wsum[NW];

    // reject chain: lanes 0..7 gather in parallel, ballot+ffs
    if (wid == 0) {
        bool rej = false;
        if (lane < SS) {
            int   tok = ids[b * SS + lane];
            float t   = target[((size_t)b * (SS + 1) + lane) * VV + tok];
            float d   = draft [((size_t)b * SS       + lane) * VV + tok];
            rej = (t / d) < ru[b * SS + lane];
        }
        unsigned long long m = __ballot(rej);
        if (lane == 0) s_rj = m ? (int)(__ffsll((long long)m) - 1) : SS;
    }
    __syncthreads();
    const int rj = s_rj;
    if (c == 0 && tid == 0) { rj_ws[b] = rj; count[b] = 0u; }

    const bool bonus = (rj == SS);
    const float* __restrict__ trow =
        target + ((size_t)b * (SS + 1) + rj) * VV + (size_t)c * CHUNK;
    const float* __restrict__ drow =
        draft  + ((size_t)b * SS + (bonus ? 0 : rj)) * VV + (size_t)c * CHUNK;

    float lsum = 0.f;
    if (tid < ACT) {
        const float4* t4 = reinterpret_cast<const float4*>(trow) + tid * 2;
        const float4* d4 = reinterpret_cast<const float4*>(drow) + tid * 2;
        #pragma unroll
        for (int k = 0; k < 2; ++k) {
            float4 t = t4[k];
            if (bonus) {
                lsum += t.x + t.y + t.z + t.w;
            } else {
                float4 d = d4[k];
                lsum += fmaxf(t.x - d.x, 0.f) + fmaxf(t.y - d.y, 0.f)
                      + fmaxf(t.z - d.z, 0.f) + fmaxf(t.w - d.w, 0.f);
            }
        }
    }
    #pragma unroll
    for (int off = 32; off > 0; off >>= 1) lsum += __shfl_down(lsum, off, 64);
    if (lane == 0) s_wsum[wid] = lsum;
    __syncthreads();
    if (tid == 0) {
        float s = 0.f;
        #pragma unroll
        for (int w = 0; w < NW; ++w) s += s_wsum[w];
        partial[blk] = s;
    }
}

__global__ __launch_bounds__(NTH) void rs_k2(
    const float* __restrict__ target, const float* __restrict__ draft,
    const int* __restrict__ ids, const float* __restrict__ su,
    const int* __restrict__ rj_ws, const float* __restrict__ partial,
    unsigned int* __restrict__ count, int* __restrict__ out)
{
    const int blk = blockIdx.x, b = blk >> 3, c = blk & (C - 1);
    const int tid = threadIdx.x, lane = tid & 63, wid = tid >> 6;
    __shared__ float    s_wtot[NW];
    __shared__ unsigned s_cnt;
    if (tid == 0) s_cnt = 0u;

    const int  rj    = rj_ws[b];
    const bool bonus = (rj == SS);
    const float* __restrict__ trow =
        target + ((size_t)b * (SS + 1) + rj) * VV + (size_t)c * CHUNK;
    const float* __restrict__ drow =
        draft  + ((size_t)b * SS + (bonus ? 0 : rj)) * VV + (size_t)c * CHUNK;

    float q[PT];
    #pragma unroll
    for (int k = 0; k < PT; ++k) q[k] = 0.f;
    float lsum = 0.f;

    if (tid < ACT) {
        const float4* t4 = reinterpret_cast<const float4*>(trow) + tid * 2;
        const float4* d4 = reinterpret_cast<const float4*>(drow) + tid * 2;
        #pragma unroll
        for (int k = 0; k < 2; ++k) {
            float4 t = t4[k];
            if (bonus) {
                q[4*k+0] = t.x; q[4*k+1] = t.y; q[4*k+2] = t.z; q[4*k+3] = t.w;
            } else {
                float4 d = d4[k];
                q[4*k+0] = fmaxf(t.x - d.x, 0.f);
                q[4*k+1] = fmaxf(t.y - d.y, 0.f);
                q[4*k+2] = fmaxf(t.z - d.z, 0.f);
                q[4*k+3] = fmaxf(t.w - d.w, 0.f);
            }
        }
        #pragma unroll
        for (int k = 0; k < PT; ++k) lsum += q[k];
    }

    // wave-level inclusive scan of per-thread sums
    float v = lsum;
    #pragma unroll
    for (int d = 1; d < 64; d <<= 1) {
        float n = __shfl_up(v, d, 64);
        if (lane >= d) v += n;
    }
    if (lane == 63) s_wtot[wid] = v;
    __syncthreads();

    float woff = 0.f;
    for (int w = 0; w < wid; ++w) woff += s_wtot[w];

    float excl = 0.f, total = 0.f;
    #pragma unroll
    for (int j = 0; j < C; ++j) {
        float p = partial[b * C + j];
        if (j < c) excl += p;
        total += p;
    }
    const float T = su[b] * total;

    float running = excl + woff + (v - lsum);   // global exclusive prefix
    int cnt = 0;
    if (tid < ACT) {
        #pragma unroll
        for (int k = 0; k < PT; ++k) {
            running += q[k];
            cnt += (running < T) ? 1 : 0;
        }
    }
    #pragma unroll
    for (int off = 32; off > 0; off >>= 1) cnt += __shfl_down(cnt, off, 64);
    if (lane == 0 && cnt) atomicAdd(&s_cnt, (unsigned)cnt);
    __syncthreads();

    if (tid == 0) {
        unsigned old = atomicAdd(&count[b], s_cnt + (1u << 20));
        if ((old >> 20) == (unsigned)(C - 1)) {       // last arrival for batch b
            int final_cnt = (int)((old & 0xFFFFFu) + s_cnt);
            int sampled   = min(final_cnt, VV - 1);
            for (int s = 0; s <= SS; ++s) {
                int val = (s < rj) ? ids[b * SS + s]
                                   : ((s == rj) ? sampled : -1);
                out[b * (SS + 1) + s] = val;
            }
        }
    }
}

extern "C" void kernel_launch(void* const* d_in, const int* in_sizes, int n_in,
                              void* d_out, int out_size, void* d_ws, size_t ws_size,
                              hipStream_t stream) {
    const float* target = (const float*)d_in[0];
    const float* draft  = (const float*)d_in[1];
    const int*   ids    = (const int*)  d_in[2];
    const float* ru     = (const float*)d_in[3];
    const float* su     = (const float*)d_in[4];
    int* out = (int*)d_out;

    int*      rj_ws   = (int*)d_ws;                                  // BB
    float*    partial = (float*)((char*)d_ws + 256);                 // BB*C
    unsigned* count   = (unsigned*)((char*)d_ws + 256 + BB * C * 4); // BB

    rs_k1<<<BB * C, NTH, 0, stream>>>(target, draft, ids, ru, rj_ws, partial, count);
    rs_k2<<<BB * C, NTH, 0, stream>>>(target, draft, ids, su, rj_ws, partial, count, out);
}